// Round 15
// baseline (588.483 us; speedup 1.0000x reference)
//
#include <hip/hip_runtime.h>
#include <hip/hip_fp16.h>
#include <math.h>

#define NB 16
#define TT 256
#define JJ 17
#define CC 512
#define HH 8
#define HD 64
#define MROWS (NB*TT*JJ)        // 69632
#define QTILE 16384             // u16 elems per (b,h,j) tile
#define NTILES (NB*HH*JJ)       // 2176
#define NQKV 35651584           // elements per plane (MROWS*512)

#define W0 0.0245436926061702596f   // 2*pi/256

typedef __attribute__((ext_vector_type(8))) short i16x8;
typedef __attribute__((ext_vector_type(8))) _Float16 f16x8;
typedef __attribute__((ext_vector_type(4))) float f32x4;

__device__ __forceinline__ unsigned short f2h(float f) {
    return (unsigned short)__half_as_ushort(__float2half(f));
}
__device__ __forceinline__ float h2f(unsigned short u) {
    return __half2float(__ushort_as_half(u));
}

#define GLD16(gp, lp) __builtin_amdgcn_global_load_lds( \
    (__attribute__((address_space(1))) void*)(gp), \
    (__attribute__((address_space(3))) void*)(lp), 16, 0, 0)

// swizzled addressing: S1/S2 are [128][64], XTMP/XT are [64][128]
#define SWZ(row, col) ((row)*64 + ((col) ^ (((row) & 7) << 3)))
#define TSW(row, col) ((row)*128 + ((col) ^ (((row) & 7) << 3)))

// ---------------- f32 -> f16 conversion (8-wide) ----------------------------
__global__ __launch_bounds__(256) void conv16_k(
    const float* __restrict__ s, unsigned short* __restrict__ d, int n8)
{
    for (int i = blockIdx.x*256 + threadIdx.x; i < n8; i += gridDim.x*256) {
        float4 a = ((const float4*)s)[i*2];
        float4 b = ((const float4*)s)[i*2+1];
        i16x8 h;
        h[0] = (short)f2h(a.x); h[1] = (short)f2h(a.y);
        h[2] = (short)f2h(a.z); h[3] = (short)f2h(a.w);
        h[4] = (short)f2h(b.x); h[5] = (short)f2h(b.y);
        h[6] = (short)f2h(b.z); h[7] = (short)f2h(b.w);
        ((i16x8*)d)[i] = h;
    }
}

// ---------------- fused prep: wq/wp conv + W + WI twiddle init --------------
__global__ __launch_bounds__(256) void prep_k(
    const float* __restrict__ wq, const float* __restrict__ wp,
    unsigned short* __restrict__ wqh, unsigned short* __restrict__ wph,
    unsigned short* __restrict__ Whi, unsigned short* __restrict__ Wlo,
    unsigned short* __restrict__ WIhi)
{
    const int b = blockIdx.x;
    const int tid = threadIdx.x;
    if (b < 512) {
        const float* s = (b < 384) ? wq : wp;
        unsigned short* d = (b < 384) ? wqh : wph;
        int i = (b < 384 ? b : b - 384)*256 + tid;
        float4 a = ((const float4*)s)[i*2];
        float4 bb = ((const float4*)s)[i*2+1];
        i16x8 h;
        h[0] = (short)f2h(a.x); h[1] = (short)f2h(a.y);
        h[2] = (short)f2h(a.z); h[3] = (short)f2h(a.w);
        h[4] = (short)f2h(bb.x); h[5] = (short)f2h(bb.y);
        h[6] = (short)f2h(bb.z); h[7] = (short)f2h(bb.w);
        ((i16x8*)d)[i] = h;
    } else if (b < 640) {
        const int r = b - 512;
        const int t = tid;
        int idx = ((r & 63) * t) & 255;
        float sv, cv;
        sincosf(W0 * (float)idx, &sv, &cv);
        float val = (r < 64) ? cv : -sv;
        unsigned short h = f2h(val);
        Whi[r*256 + t] = h;
        Wlo[r*256 + t] = f2h(val - h2f(h));
    } else {
        int idx = (b - 640)*256 + tid;
        int t = idx >> 7;
        int f = idx & 127;
        int fr = f & 63;
        int ii = (t * fr) & 255;
        float sv, cv;
        sincosf(W0 * (float)ii, &sv, &cv);
        float cf = (fr == 0 && f < 64) ? 0.5f : 1.f;
        float val = ((f < 64) ? cv : -sv) * cf * (2.f / 256.f);
        WIhi[t*128 + f] = f2h(val);
    }
}

// ---------------- GEMM 1 (f16 MFMA, BK=64): qkv = x @ w_qkv^T ---------------
__global__ __launch_bounds__(256) void gemm_qkv_k(
    const unsigned short* __restrict__ A, const unsigned short* __restrict__ B,
    unsigned short* __restrict__ qp, unsigned short* __restrict__ kp,
    unsigned short* __restrict__ vp)
{
    __shared__ unsigned short Sh[128*128];
    unsigned short* Ah = Sh;
    unsigned short* Bh = Sh + 128*64;
    const int tid = threadIdx.x;
    const int lane = tid & 63;
    const int lo = lane & 15, hi = lane >> 4;
    const int wv = tid >> 6;
    const int wr = wv >> 1, wc = wv & 1;
    const int bid = blockIdx.x;
    const int wrk = (bid & 7) * 816 + (bid >> 3);
    const int col0 = (wrk % 12) * 128;
    const int row0 = (wrk / 12) * 128;

    f32x4 acc[4][4];
    #pragma unroll
    for (int rb = 0; rb < 4; ++rb)
        #pragma unroll
        for (int cb = 0; cb < 4; ++cb) acc[rb][cb] = (f32x4){0.f,0.f,0.f,0.f};

    for (int k0 = 0; k0 < 512; k0 += 64) {
        #pragma unroll
        for (int c = 0; c < 4; ++c) {
            int e = c*2048 + tid*8;
            int r = e >> 6, cc = e & 63;
            int ccs = cc ^ ((r & 7) << 3);
            size_t offA = (size_t)(row0 + r)*512 + k0 + ccs;
            size_t offB = (size_t)(col0 + r)*512 + k0 + ccs;
            GLD16(A + offA, (char*)Ah + c*4096 + tid*16);
            GLD16(B + offB, (char*)Bh + c*4096 + tid*16);
        }
        __syncthreads();
        #pragma unroll
        for (int ks = 0; ks < 2; ++ks) {
            f16x8 af[4], bf[4];
            #pragma unroll
            for (int rb = 0; rb < 4; ++rb) {
                int row = wr*64 + rb*16 + lo;
                int col = (ks*32 + hi*8) ^ ((row & 7) << 3);
                af[rb] = *(const f16x8*)&Ah[row*64 + col];
            }
            #pragma unroll
            for (int cb = 0; cb < 4; ++cb) {
                int row = wc*64 + cb*16 + lo;
                int col = (ks*32 + hi*8) ^ ((row & 7) << 3);
                bf[cb] = *(const f16x8*)&Bh[row*64 + col];
            }
            #pragma unroll
            for (int rb = 0; rb < 4; ++rb)
                #pragma unroll
                for (int cb = 0; cb < 4; ++cb)
                    acc[rb][cb] = __builtin_amdgcn_mfma_f32_16x16x32_f16(
                        af[rb], bf[cb], acc[rb][cb], 0, 0, 0);
        }
        __syncthreads();
    }

    #pragma unroll
    for (int cb = 0; cb < 4; ++cb) {
        int n0 = col0 + wc*64 + cb*16;
        float scl = ((n0 >> 9) == 0) ? 0.125f : 1.f;
        #pragma unroll
        for (int rb = 0; rb < 4; ++rb)
            #pragma unroll
            for (int r = 0; r < 4; ++r) {
                int row = wr*64 + rb*16 + hi*4 + r;
                int col = wc*64 + cb*16 + lo;
                Sh[row*128 + (col ^ ((row & 7) << 3))] = f2h(acc[rb][cb][r]*scl);
            }
    }
    __syncthreads();

    {
        const int grp = lane >> 3;
        const int d0 = (lane & 7) * 8;
        #pragma unroll
        for (int it = 0; it < 8; ++it) {
            int p = it*32 + wv*8 + grp;
            int row = p >> 1;
            int half = p & 1;
            int m = row0 + row;
            int bb = m / (TT*JJ);
            int rem = m - bb*(TT*JJ);
            int t = rem / JJ;
            int j = rem - t*JJ;
            int n0 = col0 + half*64;
            int g = n0 >> 9;
            unsigned short* dst0 = (g == 0) ? qp : (g == 1) ? kp : vp;
            int h = (n0 >> 6) & 7;
            unsigned short* dst = dst0 +
                ((((size_t)bb*HH + h)*JJ + j)*TT + t)*HD + d0;
            i16x8 vls = *(const i16x8*)&Sh[row*128 + ((half*64 + d0) ^ ((row & 7) << 3))];
            *(i16x8*)dst = vls;
        }
    }
}

// ---------------- GEMM 2 (f16 MFMA, BK=64): out = y @ w_proj^T + b ----------
__global__ __launch_bounds__(256) void gemm_proj_k(
    const unsigned short* __restrict__ A, const unsigned short* __restrict__ B,
    const float* __restrict__ bias, float* __restrict__ out)
{
    __shared__ unsigned short Ah[128*64];
    __shared__ unsigned short Bh[128*64];
    const int tid = threadIdx.x;
    const int lane = tid & 63;
    const int lo = lane & 15, hi = lane >> 4;
    const int wv = tid >> 6;
    const int wr = wv >> 1, wc = wv & 1;
    const int bid = blockIdx.x;
    const int wrk = (bid & 7) * 272 + (bid >> 3);
    const int col0 = (wrk % 4) * 128;
    const int row0 = (wrk / 4) * 128;

    f32x4 acc[4][4];
    #pragma unroll
    for (int rb = 0; rb < 4; ++rb)
        #pragma unroll
        for (int cb = 0; cb < 4; ++cb) acc[rb][cb] = (f32x4){0.f,0.f,0.f,0.f};

    for (int k0 = 0; k0 < 512; k0 += 64) {
        #pragma unroll
        for (int c = 0; c < 4; ++c) {
            int e = c*2048 + tid*8;
            int r = e >> 6, cc = e & 63;
            int ccs = cc ^ ((r & 7) << 3);
            size_t offA = (size_t)(row0 + r)*512 + k0 + ccs;
            size_t offB = (size_t)(col0 + r)*512 + k0 + ccs;
            GLD16(A + offA, (char*)Ah + c*4096 + tid*16);
            GLD16(B + offB, (char*)Bh + c*4096 + tid*16);
        }
        __syncthreads();
        #pragma unroll
        for (int ks = 0; ks < 2; ++ks) {
            f16x8 af[4], bf[4];
            #pragma unroll
            for (int rb = 0; rb < 4; ++rb) {
                int row = wr*64 + rb*16 + lo;
                int col = (ks*32 + hi*8) ^ ((row & 7) << 3);
                af[rb] = *(const f16x8*)&Ah[row*64 + col];
            }
            #pragma unroll
            for (int cb = 0; cb < 4; ++cb) {
                int row = wc*64 + cb*16 + lo;
                int col = (ks*32 + hi*8) ^ ((row & 7) << 3);
                bf[cb] = *(const f16x8*)&Bh[row*64 + col];
            }
            #pragma unroll
            for (int rb = 0; rb < 4; ++rb)
                #pragma unroll
                for (int cb = 0; cb < 4; ++cb)
                    acc[rb][cb] = __builtin_amdgcn_mfma_f32_16x16x32_f16(
                        af[rb], bf[cb], acc[rb][cb], 0, 0, 0);
        }
        __syncthreads();
    }

    #pragma unroll
    for (int cb = 0; cb < 4; ++cb) {
        int n = col0 + wc*64 + cb*16 + lo;
        float bv = bias[n];
        #pragma unroll
        for (int rb = 0; rb < 4; ++rb)
            #pragma unroll
            for (int r = 0; r < 4; ++r) {
                int m = row0 + wr*64 + rb*16 + hi*4 + r;
                out[(size_t)m*512 + n] = acc[rb][cb][r] + bv;
            }
    }
}

// ---------------- time attention via f16 MFMA (q pre-scaled) ----------------
#define PPW 40

__global__ __launch_bounds__(256, 3) void attn_time_k(
    const unsigned short* __restrict__ q, const unsigned short* __restrict__ k,
    const unsigned short* __restrict__ v, const float* __restrict__ fg,
    unsigned short* __restrict__ y)
{
    __shared__ unsigned short VT[64 * 256];
    __shared__ unsigned short PL[4 * 64 * PPW];

    const int bid = blockIdx.x;
    const int b = bid / (HH*JJ);
    const int h = (bid / JJ) % HH;
    const int j = bid % JJ;
    const size_t base = (size_t)bid * QTILE;

    const int tid = threadIdx.x;
    const int w = tid >> 6;
    const int lane = tid & 63;
    const int lo = lane & 15;
    const int hi = lane >> 4;

    {
        const unsigned short* vptr = v + base + (size_t)tid * HD;
        #pragma unroll
        for (int d0 = 0; d0 < 64; d0 += 8) {
            i16x8 vv = *(const i16x8*)(vptr + d0);
            #pragma unroll
            for (int e = 0; e < 8; ++e) {
                int row = d0 + e;
                VT[row*256 + (tid ^ ((row & 7) << 3))] = (unsigned short)vv[e];
            }
        }
    }
    __syncthreads();

    f16x8 qf[4][2];
    #pragma unroll
    for (int rb = 0; rb < 4; ++rb)
        #pragma unroll
        for (int dc = 0; dc < 2; ++dc)
            qf[rb][dc] = *(const f16x8*)(q + base + (size_t)(w*64 + rb*16 + lo)*HD + dc*32 + hi*8);

    f32x4 o[4][4];
    #pragma unroll
    for (int rb = 0; rb < 4; ++rb)
        #pragma unroll
        for (int cd = 0; cd < 4; ++cd) o[rb][cd] = (f32x4){0.f,0.f,0.f,0.f};
    float rs[4][4];
    #pragma unroll
    for (int rb = 0; rb < 4; ++rb)
        #pragma unroll
        for (int r = 0; r < 4; ++r) rs[rb][r] = 0.f;

    unsigned short* Pw = PL + w * 64 * PPW;

    for (int st = 0; st < 8; ++st) {
        const int s0 = st * 32;
        f16x8 kf[2][2];
        #pragma unroll
        for (int cb = 0; cb < 2; ++cb)
            #pragma unroll
            for (int dc = 0; dc < 2; ++dc)
                kf[cb][dc] = *(const f16x8*)(k + base + (size_t)(s0 + cb*16 + lo)*HD + dc*32 + hi*8);

        #pragma unroll
        for (int rb = 0; rb < 4; ++rb) {
            #pragma unroll
            for (int cb = 0; cb < 2; ++cb) {
                f32x4 acc = (f32x4){0.f,0.f,0.f,0.f};
                acc = __builtin_amdgcn_mfma_f32_16x16x32_f16(qf[rb][0], kf[cb][0], acc, 0, 0, 0);
                acc = __builtin_amdgcn_mfma_f32_16x16x32_f16(qf[rb][1], kf[cb][1], acc, 0, 0, 0);
                #pragma unroll
                for (int r = 0; r < 4; ++r) {
                    float p = __expf(acc[r]);
                    rs[rb][r] += p;
                    Pw[(rb*16 + hi*4 + r)*PPW + cb*16 + lo] = f2h(p);
                }
            }
        }

        f16x8 pa[4];
        #pragma unroll
        for (int rb = 0; rb < 4; ++rb)
            pa[rb] = *(const f16x8*)&Pw[(rb*16 + lo)*PPW + hi*8];
        f16x8 bv[4];
        #pragma unroll
        for (int cd = 0; cd < 4; ++cd) {
            int row = cd*16 + lo;
            bv[cd] = *(const f16x8*)&VT[row*256 + ((s0 + hi*8) ^ ((row & 7) << 3))];
        }
        #pragma unroll
        for (int rb = 0; rb < 4; ++rb)
            #pragma unroll
            for (int cd = 0; cd < 4; ++cd)
                o[rb][cd] = __builtin_amdgcn_mfma_f32_16x16x32_f16(pa[rb], bv[cd], o[rb][cd], 0, 0, 0);
    }

    #pragma unroll
    for (int off = 1; off < 16; off <<= 1)
        #pragma unroll
        for (int rb = 0; rb < 4; ++rb)
            #pragma unroll
            for (int r = 0; r < 4; ++r)
                rs[rb][r] += __shfl_xor(rs[rb][r], off, 64);

    const float gate = 1.f / (1.f + __expf(-fg[0]));
    const float wt = 1.f - gate;
    #pragma unroll
    for (int rb = 0; rb < 4; ++rb) {
        #pragma unroll
        for (int r = 0; r < 4; ++r) {
            const int t = w*64 + rb*16 + hi*4 + r;
            const float sc = wt / rs[rb][r];
            unsigned short* yp = y + (((size_t)b*TT + t)*JJ + j)*CC + h*HD;
            #pragma unroll
            for (int cd = 0; cd < 4; ++cd)
                yp[cd*16 + lo] = f2h(o[rb][cd][r] * sc);
        }
    }
}

// ---------------- DFT of one plane (fused helper) ---------------------------
// dacc[rb][cd] = W[128][256] @ X[256][64] for this wave's rows; X staged
// transposed in two 64x128 halves through XTMP (swizzled).
__device__ __forceinline__ void dft_plane(
    const unsigned short* __restrict__ src, const unsigned short* __restrict__ Whi,
    const unsigned short* __restrict__ Wlo, unsigned short* XTMP,
    int tid, f32x4 dacc[2][4], bool useLo)
{
    const int w = tid >> 6;
    const int lane = tid & 63;
    const int lo = lane & 15, hi = lane >> 4;
    const int qd = (tid >> 4) & 3;
    const int rr = tid & 15;

    #pragma unroll
    for (int rb = 0; rb < 2; ++rb)
        #pragma unroll
        for (int cd = 0; cd < 4; ++cd) dacc[rb][cd] = (f32x4){0.f,0.f,0.f,0.f};

    for (int hf = 0; hf < 2; ++hf) {
        __syncthreads();   // XTMP free (previous consumers done)
        #pragma unroll
        for (int p = 0; p < 8; ++p) {
            const int tloc = p*16 + 4*w + qd;
            const int t = hf*128 + tloc;
            ushort4 x4 = *(const ushort4*)&src[t*64 + 4*rr];
            unsigned int a0 = x4.x, a1 = x4.y, a2 = x4.z, a3 = x4.w;
            unsigned int t01 = (unsigned)__shfl_xor((int)((qd&1) ? a0 : a1), 16, 64);
            unsigned int t23 = (unsigned)__shfl_xor((int)((qd&1) ? a2 : a3), 16, 64);
            if (qd&1) { a0 = t01; a2 = t23; } else { a1 = t01; a3 = t23; }
            unsigned int u01 = (unsigned)__shfl_xor((int)((qd&2) ? a0 : a2), 32, 64);
            unsigned int u23 = (unsigned)__shfl_xor((int)((qd&2) ? a1 : a3), 32, 64);
            if (qd&2) { a0 = u01; a1 = u23; } else { a2 = u01; a3 = u23; }
            const int dd = 4*rr + qd;
            const int tb = p*16 + 4*w;
            ushort4 hv;
            hv.x = (unsigned short)a0; hv.y = (unsigned short)a1;
            hv.z = (unsigned short)a2; hv.w = (unsigned short)a3;
            *(ushort4*)&XTMP[dd*128 + (tb ^ ((dd & 7) << 3))] = hv;
        }
        __syncthreads();
        #pragma unroll
        for (int ks = 0; ks < 4; ++ks) {
            const int k0 = ks*32;
            f16x8 ah[2], al[2];
            #pragma unroll
            for (int rb = 0; rb < 2; ++rb) {
                int rw = w*32 + rb*16 + lo;
                ah[rb] = *(const f16x8*)&Whi[rw*256 + hf*128 + k0 + hi*8];
                if (useLo) al[rb] = *(const f16x8*)&Wlo[rw*256 + hf*128 + k0 + hi*8];
            }
            f16x8 bh[4];
            #pragma unroll
            for (int cd = 0; cd < 4; ++cd) {
                int d = cd*16 + lo;
                bh[cd] = *(const f16x8*)&XTMP[TSW(d, k0 + hi*8)];
            }
            #pragma unroll
            for (int rb = 0; rb < 2; ++rb)
                #pragma unroll
                for (int cd = 0; cd < 4; ++cd) {
                    dacc[rb][cd] = __builtin_amdgcn_mfma_f32_16x16x32_f16(
                        ah[rb], bh[cd], dacc[rb][cd], 0, 0, 0);
                    if (useLo)
                        dacc[rb][cd] = __builtin_amdgcn_mfma_f32_16x16x32_f16(
                            al[rb], bh[cd], dacc[rb][cd], 0, 0, 0);
                }
        }
    }
}

// ---------------- fused freq branch: dft(q,k,v) -> af -> dual softmax ->
// xf -> irfft -> y. All matmuls MFMA; no intermediate HBM traffic.
__global__ __launch_bounds__(256) void freqtail_k(
    const unsigned short* __restrict__ qp, const unsigned short* __restrict__ kp,
    const unsigned short* __restrict__ vp, const unsigned short* __restrict__ Whi,
    const unsigned short* __restrict__ Wlo, const unsigned short* __restrict__ WIhi,
    const float* __restrict__ fg, unsigned short* __restrict__ y)
{
    __shared__ unsigned short S1[128*64];    // qf -> P -> XT([64][128])
    __shared__ unsigned short S2[128*64];    // kf -> VFT
    __shared__ unsigned short XTMP[64*128];  // plane^T staging

    const int tid = threadIdx.x;
    const int tile = blockIdx.x;
    const int b = tile / (HH*JJ);
    const int h = (tile / JJ) % HH;
    const int j = tile % JJ;
    const unsigned short* qsrc = qp + (size_t)tile * QTILE;
    const unsigned short* ksrc = kp + (size_t)tile * QTILE;
    const unsigned short* vsrc = vp + (size_t)tile * QTILE;

    const int w = tid >> 6;
    const int lane = tid & 63;
    const int lo = lane & 15, hi = lane >> 4;
    const int comp = w >> 1;
    const int fr0 = (w & 1) * 32;

    f32x4 dacc[2][4];

    // ---- qf = W @ q -> S1 ----
    dft_plane(qsrc, Whi, Wlo, XTMP, tid, dacc, true);
    #pragma unroll
    for (int rb = 0; rb < 2; ++rb)
        #pragma unroll
        for (int cd = 0; cd < 4; ++cd)
            #pragma unroll
            for (int r = 0; r < 4; ++r) {
                int row = w*32 + rb*16 + hi*4 + r;
                S1[SWZ(row, cd*16 + lo)] = f2h(dacc[rb][cd][r]);
            }

    // ---- kf = W @ k -> S2 ----
    dft_plane(ksrc, Whi, Wlo, XTMP, tid, dacc, true);
    #pragma unroll
    for (int rb = 0; rb < 2; ++rb)
        #pragma unroll
        for (int cd = 0; cd < 4; ++cd)
            #pragma unroll
            for (int r = 0; r < 4; ++r) {
                int row = w*32 + rb*16 + hi*4 + r;
                S2[SWZ(row, cd*16 + lo)] = f2h(dacc[rb][cd][r]);
            }
    __syncthreads();

    // ---- af via MFMA ----
    f32x4 accA[2][4], accB[2][4];
    #pragma unroll
    for (int rb = 0; rb < 2; ++rb)
        #pragma unroll
        for (int cb = 0; cb < 4; ++cb) {
            accA[rb][cb] = (f32x4){0.f,0.f,0.f,0.f};
            accB[rb][cb] = (f32x4){0.f,0.f,0.f,0.f};
        }
    #pragma unroll
    for (int ks = 0; ks < 2; ++ks) {
        f16x8 qA[2], qB[2];
        #pragma unroll
        for (int rb = 0; rb < 2; ++rb) {
            int fr = fr0 + rb*16 + lo;
            qA[rb] = *(const f16x8*)&S1[SWZ(comp*64 + fr, ks*32 + hi*8)];
            qB[rb] = *(const f16x8*)&S1[SWZ((1-comp)*64 + fr, ks*32 + hi*8)];
        }
        f16x8 kr[4], ki[4];
        #pragma unroll
        for (int cb = 0; cb < 4; ++cb) {
            int g = cb*16 + lo;
            kr[cb] = *(const f16x8*)&S2[SWZ(g, ks*32 + hi*8)];
            ki[cb] = *(const f16x8*)&S2[SWZ(64 + g, ks*32 + hi*8)];
        }
        #pragma unroll
        for (int rb = 0; rb < 2; ++rb)
            #pragma unroll
            for (int cb = 0; cb < 4; ++cb) {
                accA[rb][cb] = __builtin_amdgcn_mfma_f32_16x16x32_f16(
                    qA[rb], kr[cb], accA[rb][cb], 0, 0, 0);
                accB[rb][cb] = __builtin_amdgcn_mfma_f32_16x16x32_f16(
                    qB[rb], ki[cb], accB[rb][cb], 0, 0, 0);
            }
    }
    __syncthreads();   // S1/S2 reads done

    // ---- in-register dual softmax ----
    const float sgn = comp ? -1.f : 1.f;
    float pv[2][4][4];
    float inv[2][4];
    #pragma unroll
    for (int rb = 0; rb < 2; ++rb) {
        #pragma unroll
        for (int r = 0; r < 4; ++r) {
            float m = -3.0e38f;
            #pragma unroll
            for (int cb = 0; cb < 4; ++cb) {
                float vv = accA[rb][cb][r] + sgn*accB[rb][cb][r];
                pv[rb][cb][r] = vv;
                m = fmaxf(m, vv);
            }
            #pragma unroll
            for (int off = 1; off < 16; off <<= 1)
                m = fmaxf(m, __shfl_xor(m, off, 64));
            float s = 0.f;
            #pragma unroll
            for (int cb = 0; cb < 4; ++cb) {
                float e = __expf(pv[rb][cb][r] - m);
                pv[rb][cb][r] = e;
                s += e;
            }
            #pragma unroll
            for (int off = 1; off < 16; off <<= 1)
                s += __shfl_xor(s, off, 64);
            inv[rb][r] = 1.f / s;
        }
    }
    // P -> S1
    #pragma unroll
    for (int rb = 0; rb < 2; ++rb)
        #pragma unroll
        for (int r = 0; r < 4; ++r)
            #pragma unroll
            for (int cb = 0; cb < 4; ++cb)
                S1[SWZ(w*32 + rb*16 + hi*4 + r, cb*16 + lo)] =
                    f2h(pv[rb][cb][r] * inv[rb][r]);

    // ---- vf = W @ v (1-product) -> VFT (transposed) in S2 ----
    dft_plane(vsrc, Whi, Wlo, XTMP, tid, dacc, false);
    #pragma unroll
    for (int rb = 0; rb < 2; ++rb)
        #pragma unroll
        for (int cd = 0; cd < 4; ++cd)
            #pragma unroll
            for (int r = 0; r < 4; ++r) {
                int gr = w*32 + rb*16 + hi*4 + r;      // vf row (comp*64+g)
                int rowv = (gr >> 6)*64 + cd*16 + lo;  // VFT row = c2*64 + d
                S2[SWZ(rowv, gr & 63)] = f2h(dacc[rb][cd][r]);
            }
    __syncthreads();

    // ---- xf via MFMA ----
    f32x4 xA[2][4], xB[2][4];
    #pragma unroll
    for (int rb = 0; rb < 2; ++rb)
        #pragma unroll
        for (int cd = 0; cd < 4; ++cd) {
            xA[rb][cd] = (f32x4){0.f,0.f,0.f,0.f};
            xB[rb][cd] = (f32x4){0.f,0.f,0.f,0.f};
        }
    #pragma unroll
    for (int ks = 0; ks < 2; ++ks) {
        f16x8 pA[2], pB[2];
        #pragma unroll
        for (int rb = 0; rb < 2; ++rb) {
            int fr = fr0 + rb*16 + lo;
            pA[rb] = *(const f16x8*)&S1[SWZ(fr, ks*32 + hi*8)];
            pB[rb] = *(const f16x8*)&S1[SWZ(64 + fr, ks*32 + hi*8)];
        }
        f16x8 bA[4], bB[4];
        #pragma unroll
        for (int cd = 0; cd < 4; ++cd) {
            int d = cd*16 + lo;
            bA[cd] = *(const f16x8*)&S2[SWZ(comp*64 + d, ks*32 + hi*8)];
            bB[cd] = *(const f16x8*)&S2[SWZ((1-comp)*64 + d, ks*32 + hi*8)];
        }
        #pragma unroll
        for (int rb = 0; rb < 2; ++rb)
            #pragma unroll
            for (int cd = 0; cd < 4; ++cd) {
                xA[rb][cd] = __builtin_amdgcn_mfma_f32_16x16x32_f16(
                    pA[rb], bA[cd], xA[rb][cd], 0, 0, 0);
                xB[rb][cd] = __builtin_amdgcn_mfma_f32_16x16x32_f16(
                    pB[rb], bB[cd], xB[rb][cd], 0, 0, 0);
            }
    }
    __syncthreads();   // P/VFT reads done

    // ---- XT (xf transposed, [64][128]) over S1 ----
    const float sgn2 = comp ? 1.f : -1.f;
    unsigned short* XT = S1;
    #pragma unroll
    for (int rb = 0; rb < 2; ++rb)
        #pragma unroll
        for (int cd = 0; cd < 4; ++cd)
            #pragma unroll
            for (int r = 0; r < 4; ++r) {
                int f = fr0 + rb*16 + hi*4 + r;
                int d = cd*16 + lo;
                XT[TSW(d, comp*64 + f)] =
                    f2h(xA[rb][cd][r] + sgn2*xB[rb][cd][r]);
            }
    __syncthreads();

    // ---- irfft MFMA tail ----
    f32x4 acc[4][4];
    #pragma unroll
    for (int rb = 0; rb < 4; ++rb)
        #pragma unroll
        for (int cd = 0; cd < 4; ++cd) acc[rb][cd] = (f32x4){0.f,0.f,0.f,0.f};

    #pragma unroll
    for (int ks = 0; ks < 4; ++ks) {
        const int k0 = ks*32;
        f16x8 ah[4];
        #pragma unroll
        for (int rb = 0; rb < 4; ++rb) {
            int row = w*64 + rb*16 + lo;
            ah[rb] = *(const f16x8*)&WIhi[row*128 + k0 + hi*8];
        }
        f16x8 bt[4];
        #pragma unroll
        for (int cd = 0; cd < 4; ++cd) {
            int d = cd*16 + lo;
            bt[cd] = *(const f16x8*)&XT[TSW(d, k0 + hi*8)];
        }
        #pragma unroll
        for (int rb = 0; rb < 4; ++rb)
            #pragma unroll
            for (int cd = 0; cd < 4; ++cd)
                acc[rb][cd] = __builtin_amdgcn_mfma_f32_16x16x32_f16(
                    ah[rb], bt[cd], acc[rb][cd], 0, 0, 0);
    }

    const float gate = 1.f / (1.f + __expf(-fg[0]));
    #pragma unroll
    for (int rb = 0; rb < 4; ++rb) {
        #pragma unroll
        for (int r = 0; r < 4; ++r) {
            int t = w*64 + rb*16 + hi*4 + r;
            unsigned short* yp = y + (((size_t)b*TT + t)*JJ + j)*CC + h*HD;
            #pragma unroll
            for (int cd = 0; cd < 4; ++cd) {
                int d = cd*16 + lo;
                yp[d] = f2h(fmaf(gate, acc[rb][cd][r], h2f(yp[d])));
            }
        }
    }
}

// ---------------------------------------------------------------------------
extern "C" void kernel_launch(void* const* d_in, const int* in_sizes, int n_in,
                              void* d_out, int out_size, void* d_ws, size_t ws_size,
                              hipStream_t stream) {
    const float* x      = (const float*)d_in[0];
    const float* w_qkv  = (const float*)d_in[1];
    const float* w_proj = (const float*)d_in[2];
    const float* b_proj = (const float*)d_in[3];
    const float* fg     = (const float*)d_in[4];
    float* out = (float*)d_out;

    unsigned short* qp = (unsigned short*)d_ws;
    unsigned short* kp = qp + NQKV;
    unsigned short* vp = kp + NQKV;
    unsigned short* xh = vp + NQKV;
    unsigned short* y  = xh + NQKV;
    unsigned short* wph = y + NQKV;
    unsigned short* wqh = (unsigned short*)d_out;
    unsigned short* Whi  = wqh + 1536*512;   // 128*256
    unsigned short* Wlo  = Whi + 128*256;
    unsigned short* WIhi = Wlo + 128*256;    // 256*128

    conv16_k<<<2048, 256, 0, stream>>>(x, xh, NQKV/8);
    prep_k<<<768, 256, 0, stream>>>(w_qkv, w_proj, wqh, wph, Whi, Wlo, WIhi);

    gemm_qkv_k<<<6528, 256, 0, stream>>>(xh, wqh, qp, kp, vp);
    attn_time_k<<<NTILES, 256, 0, stream>>>(qp, kp, vp, fg, y);
    freqtail_k<<<NTILES, 256, 0, stream>>>(qp, kp, vp, Whi, Wlo, WIhi, fg, y);

    gemm_proj_k<<<2176, 256, 0, stream>>>(y, wph, b_proj, out);
}